// Round 1
// baseline (79.986 us; speedup 1.0000x reference)
//
#include <hip/hip_runtime.h>
#include <math.h>

#define S 96
#define SM 95   // S-1 midpoints

// ---------------------------------------------------------------------------
// ws[0] = global min depth bits, ws[1] = global max depth bits (positive
// floats -> int bit-pattern ordering matches float ordering).
// ---------------------------------------------------------------------------
__global__ void init_ws_kernel(unsigned int* ws) {
    ws[0] = 0x7F800000u;  // +inf
    ws[1] = 0xFF800000u;  // -inf
}

// Depths are sorted along the sample axis (reference sorts them), so the
// global min is min over rays of d[0] and global max is max over rays of
// d[S-1].
__global__ void minmax_kernel(const float* __restrict__ depths,
                              unsigned int* __restrict__ ws, int nrays) {
    int r = blockIdx.x * blockDim.x + threadIdx.x;
    float dmin = INFINITY, dmax = -INFINITY;
    if (r < nrays) {
        dmin = depths[(size_t)r * S];
        dmax = depths[(size_t)r * S + (S - 1)];
    }
#pragma unroll
    for (int off = 32; off >= 1; off >>= 1) {
        dmin = fminf(dmin, __shfl_xor(dmin, off));
        dmax = fmaxf(dmax, __shfl_xor(dmax, off));
    }
    if ((threadIdx.x & 63) == 0) {
        atomicMin((int*)&ws[0], __float_as_int(dmin));
        atomicMax((int*)&ws[1], __float_as_int(dmax));
    }
}

// ---------------------------------------------------------------------------
// One wave (64 lanes) per ray. Midpoints i = 0..94:
//   batch a: i = lane        (lanes 0..63)
//   batch b: i = 64 + lane   (lanes 0..30)
// Transmittance via multiplicative Hillis-Steele shuffle scan.
// ---------------------------------------------------------------------------
__global__ __launch_bounds__(256) void march_kernel(
    const float* __restrict__ colors,
    const float* __restrict__ dens,
    const float* __restrict__ depths,
    const int* __restrict__ white_back,
    const unsigned int* __restrict__ ws,
    float* __restrict__ out_rgb,   // [nrays,3]
    float* __restrict__ out_dep,   // [nrays]
    float* __restrict__ out_w,     // [nrays,95]
    int nrays) {
    const int wave = blockIdx.x * (blockDim.x >> 6) + (threadIdx.x >> 6);
    if (wave >= nrays) return;
    const int l = threadIdx.x & 63;
    const size_t ray = (size_t)wave;

    const float* db = depths + ray * S;
    const float* sb = dens + ray * S;
    const float* cb = colors + ray * (S * 3);

    // batch-a sample loads (sample index = l), coalesced
    float d_a = db[l];
    float s_a = sb[l];
    float c0_a = cb[3 * l + 0];
    float c1_a = cb[3 * l + 1];
    float c2_a = cb[3 * l + 2];

    // batch-b sample loads (sample index = 64 + l), lanes 0..31
    float d_b = 0.f, s_b = 0.f, c0_b = 0.f, c1_b = 0.f, c2_b = 0.f;
    if (l < 32) {
        d_b = db[64 + l];
        s_b = sb[64 + l];
        c0_b = cb[192 + 3 * l + 0];
        c1_b = cb[192 + 3 * l + 1];
        c2_b = cb[192 + 3 * l + 2];
    }

    // next-sample values: batch a needs X[l+1]; lane 63 needs X[64] (lane 0's b)
    float dn_a = __shfl_down(d_a, 1);
    float sn_a = __shfl_down(s_a, 1);
    float c0n_a = __shfl_down(c0_a, 1);
    float c1n_a = __shfl_down(c1_a, 1);
    float c2n_a = __shfl_down(c2_a, 1);
    {
        float d64 = __shfl(d_b, 0);
        float s64 = __shfl(s_b, 0);
        float c064 = __shfl(c0_b, 0);
        float c164 = __shfl(c1_b, 0);
        float c264 = __shfl(c2_b, 0);
        if (l == 63) {
            dn_a = d64; sn_a = s64;
            c0n_a = c064; c1n_a = c164; c2n_a = c264;
        }
    }
    // batch b needs X[65+l]; valid for l <= 30 (comes from lanes 1..31)
    float dn_b = __shfl_down(d_b, 1);
    float sn_b = __shfl_down(s_b, 1);
    float c0n_b = __shfl_down(c0_b, 1);
    float c1n_b = __shfl_down(c1_b, 1);
    float c2n_b = __shfl_down(c2_b, 1);

    // --- batch a midpoint math (i = l, all lanes valid: i <= 63 < 95)
    float delta_a = dn_a - d_a;
    float dmid_a = 0.5f * (d_a + dn_a);
    float smid_a = 0.5f * (s_a + sn_a);
    float sp_a = fmaxf(smid_a, 0.f) + log1pf(expf(-fabsf(smid_a)));  // softplus
    float e_a = expf(-sp_a * delta_a);
    float alpha_a = 1.0f - e_a;
    float t_a = (1.0f - alpha_a) + 1e-10f;

    // --- batch b midpoint math (i = 64 + l, valid l <= 30)
    const bool vb = (l <= 30);
    float delta_b = dn_b - d_b;
    float dmid_b = 0.5f * (d_b + dn_b);
    float smid_b = 0.5f * (s_b + sn_b);
    float sp_b = fmaxf(smid_b, 0.f) + log1pf(expf(-fabsf(smid_b)));
    float e_b = expf(-sp_b * delta_b);
    float alpha_b = vb ? (1.0f - e_b) : 0.0f;
    float t_b = vb ? ((1.0f - alpha_b) + 1e-10f) : 1.0f;

    // --- inclusive multiplicative scan of t_a across the wave
    float p = t_a;
#pragma unroll
    for (int off = 1; off < 64; off <<= 1) {
        float q = __shfl_up(p, off);
        if (l >= off) p *= q;
    }
    float T_a = __shfl_up(p, 1);          // exclusive prefix
    if (l == 0) T_a = 1.0f;
    float P64 = __shfl(p, 63);            // product of all 64 batch-a terms

    float pb = t_b;                        // invalid lanes contribute 1.0
#pragma unroll
    for (int off = 1; off < 64; off <<= 1) {
        float q = __shfl_up(pb, off);
        if (l >= off) pb *= q;
    }
    float T_b = __shfl_up(pb, 1);
    if (l == 0) T_b = 1.0f;
    T_b *= P64;

    float w_a = alpha_a * T_a;
    float w_b = vb ? (alpha_b * T_b) : 0.0f;

    // --- weighted sums across the ray
    float r_sum = w_a * (0.5f * (c0_a + c0n_a)) + w_b * (0.5f * (c0_b + c0n_b));
    float g_sum = w_a * (0.5f * (c1_a + c1n_a)) + w_b * (0.5f * (c1_b + c1n_b));
    float b_sum = w_a * (0.5f * (c2_a + c2n_a)) + w_b * (0.5f * (c2_b + c2n_b));
    float dep_sum = w_a * dmid_a + w_b * dmid_b;
    float wtot = w_a + w_b;
#pragma unroll
    for (int off = 32; off >= 1; off >>= 1) {
        r_sum += __shfl_xor(r_sum, off);
        g_sum += __shfl_xor(g_sum, off);
        b_sum += __shfl_xor(b_sum, off);
        dep_sum += __shfl_xor(dep_sum, off);
        wtot += __shfl_xor(wtot, off);
    }

    // --- outputs
    float* wout = out_w + ray * SM;
    wout[l] = w_a;                 // midpoints 0..63
    if (vb) wout[64 + l] = w_b;    // midpoints 64..94

    if (l == 0) {
        float rr = r_sum, gg = g_sum, bb = b_sum;
        if (*white_back) {
            float c = 1.0f - wtot;
            rr += c; gg += c; bb += c;
        }
        out_rgb[ray * 3 + 0] = rr;
        out_rgb[ray * 3 + 1] = gg;
        out_rgb[ray * 3 + 2] = bb;

        float gmin = __int_as_float((int)ws[0]);
        float gmax = __int_as_float((int)ws[1]);
        float cd = dep_sum;
        if (isnan(cd)) cd = INFINITY;          // nan_to_num(nan=inf)
        cd = fminf(fmaxf(cd, gmin), gmax);     // clip; inf -> gmax
        out_dep[ray] = cd;
    }
}

extern "C" void kernel_launch(void* const* d_in, const int* in_sizes, int n_in,
                              void* d_out, int out_size, void* d_ws, size_t ws_size,
                              hipStream_t stream) {
    const float* colors = (const float*)d_in[0];
    const float* dens = (const float*)d_in[1];
    const float* depths = (const float*)d_in[2];
    const int* white_back = (const int*)d_in[3];

    const int nrays = in_sizes[1] / S;  // densities: nrays * S
    unsigned int* ws = (unsigned int*)d_ws;

    float* out_rgb = (float*)d_out;                     // nrays*3
    float* out_dep = out_rgb + (size_t)nrays * 3;       // nrays
    float* out_w = out_dep + nrays;                     // nrays*95

    init_ws_kernel<<<1, 1, 0, stream>>>(ws);
    minmax_kernel<<<(nrays + 255) / 256, 256, 0, stream>>>(depths, ws, nrays);

    const int waves_per_block = 4;  // 256 threads
    const int blocks = (nrays + waves_per_block - 1) / waves_per_block;
    march_kernel<<<blocks, waves_per_block * 64, 0, stream>>>(
        colors, dens, depths, white_back, ws, out_rgb, out_dep, out_w, nrays);
}

// Round 3
// 72.377 us; speedup vs baseline: 1.1051x; 1.1051x over previous
//
#include <hip/hip_runtime.h>
#include <math.h>

#define S 96
#define SM 95   // S-1 midpoints
#define L2E 1.4426950408889634f

__device__ __forceinline__ float fast_exp2(float x) {
#if __has_builtin(__builtin_amdgcn_exp2f)
    return __builtin_amdgcn_exp2f(x);   // v_exp_f32: 2^x
#else
    return exp2f(x);
#endif
}

__device__ __forceinline__ float fast_log2(float x) {
#if __has_builtin(__builtin_amdgcn_logf)
    return __builtin_amdgcn_logf(x);    // v_log_f32: log2(x)
#else
    return log2f(x);
#endif
}

// ---------------------------------------------------------------------------
// ws[0] = global min depth bits, ws[1] = global max depth bits (positive
// floats -> int bit-pattern ordering matches float ordering).
// ---------------------------------------------------------------------------
__global__ void init_ws_kernel(unsigned int* ws) {
    ws[0] = 0x7F800000u;  // +inf
    ws[1] = 0xFF800000u;  // -inf
}

// Depths sorted along sample axis: global min = min over rays of d[0],
// global max = max over rays of d[S-1].
__global__ void minmax_kernel(const float* __restrict__ depths,
                              unsigned int* __restrict__ ws, int nrays) {
    int r = blockIdx.x * blockDim.x + threadIdx.x;
    float dmin = INFINITY, dmax = -INFINITY;
    if (r < nrays) {
        dmin = depths[(size_t)r * S];
        dmax = depths[(size_t)r * S + (S - 1)];
    }
#pragma unroll
    for (int off = 32; off >= 1; off >>= 1) {
        dmin = fminf(dmin, __shfl_xor(dmin, off));
        dmax = fmaxf(dmax, __shfl_xor(dmax, off));
    }
    if ((threadIdx.x & 63) == 0) {
        atomicMin((int*)&ws[0], __float_as_int(dmin));
        atomicMax((int*)&ws[1], __float_as_int(dmax));
    }
}

// ---------------------------------------------------------------------------
// One wave per ray. Samples j=0..95: batch a = lane l (j=l), batch b =
// lane l (j=64+l, valid l<32). Midpoints i=0..94.
//
// Log-space transmittance: dd2_i = (d_{i+1}-d_i) * log2(1+exp(x_i)),
// x_i = 0.5*(s_i+s_{i+1}).  T_j = exp2(-sum_{i<j} dd2_i).
//   w_i = T_i - T_{i+1}                      (1e-10 term negligible)
//   rgb = sum_j v_j*c_j,  dep = sum_j v_j*d_j,  v_j = 0.5*(T_{j-1}-T_{j+1})
//   (T_{-1}:=T_0=1; fake midpoint 95 has dd2=0 so T_96:=T_95)
//   wtot = 1 - T_95 (telescoping), so 1-wtot = T_95
// ---------------------------------------------------------------------------
__global__ __launch_bounds__(256) void march_kernel(
    const float* __restrict__ colors,
    const float* __restrict__ dens,
    const float* __restrict__ depths,
    const int* __restrict__ white_back,
    const unsigned int* __restrict__ ws,
    float* __restrict__ out_rgb,   // [nrays,3]
    float* __restrict__ out_dep,   // [nrays]
    float* __restrict__ out_w,     // [nrays,95]
    int nrays) {
    const int wave = blockIdx.x * (blockDim.x >> 6) + (threadIdx.x >> 6);
    if (wave >= nrays) return;
    const int l = threadIdx.x & 63;
    const size_t ray = (size_t)wave;

    const float* db = depths + ray * S;
    const float* sb = dens + ray * S;
    const float* cb = colors + ray * (S * 3);

    // batch-a loads (sample j = l), coalesced
    float d_a = db[l];
    float s_a = sb[l];
    float c0_a = cb[3 * l + 0];
    float c1_a = cb[3 * l + 1];
    float c2_a = cb[3 * l + 2];

    // batch-b loads (sample j = 64+l), lanes 0..31
    const bool hb = (l < 32);
    float d_b = 0.f, s_b = 0.f, c0_b = 0.f, c1_b = 0.f, c2_b = 0.f;
    if (hb) {
        d_b = db[64 + l];
        s_b = sb[64 + l];
        c0_b = cb[192 + 3 * l + 0];
        c1_b = cb[192 + 3 * l + 1];
        c2_b = cb[192 + 3 * l + 2];
    }

    // neighbor depth/density (only these two need next-sample values)
    float dn_a = __shfl_down(d_a, 1);
    float sn_a = __shfl_down(s_a, 1);
    {
        float d64 = __shfl(d_b, 0);
        float s64 = __shfl(s_b, 0);
        if (l == 63) { dn_a = d64; sn_a = s64; }
    }
    float dn_b = __shfl_down(d_b, 1);
    float sn_b = __shfl_down(s_b, 1);

    // log2-space density*delta per midpoint
    float x_a = 0.5f * (s_a + sn_a);
    float lg_a = fmaxf(x_a, 0.f) * L2E +
                 fast_log2(1.f + fast_exp2(-fabsf(x_a) * L2E));
    float dd_a = (dn_a - d_a) * lg_a;   // midpoint i = l  (all valid)

    float x_b = 0.5f * (s_b + sn_b);
    float lg_b = fmaxf(x_b, 0.f) * L2E +
                 fast_log2(1.f + fast_exp2(-fabsf(x_b) * L2E));
    float dd_b = (l <= 30) ? (dn_b - d_b) * lg_b : 0.f;  // midpoint 64+l

    // inclusive additive scans
    float A = dd_a;
#pragma unroll
    for (int off = 1; off < 64; off <<= 1) {
        float q = __shfl_up(A, off);
        if (l >= off) A += q;
    }
    float P = __shfl(A, 63);            // total batch-a sum
    float Bc = dd_b;
#pragma unroll
    for (int off = 1; off < 64; off <<= 1) {
        float q = __shfl_up(Bc, off);
        if (l >= off) Bc += q;
    }

    float Ti_a = fast_exp2(-A);         // T_{l+1}
    float Ti_b = fast_exp2(-(P + Bc));  // T_{65+l}  (l=31: T_96:=T_95)
    float T64 = __shfl(Ti_a, 63);       // T_64

    float Te_a = __shfl_up(Ti_a, 1);    // T_l
    if (l == 0) Te_a = 1.f;
    float Te_b = __shfl_up(Ti_b, 1);    // T_{64+l}
    if (l == 0) Te_b = T64;

    float w_a = Te_a - Ti_a;            // weight of midpoint l
    float w_b = Te_b - Ti_b;            // weight of midpoint 64+l (l<=30)

    // per-sample coefficient v_j = 0.5*(T_{j-1} - T_{j+1})
    float Tm1_a = __shfl_up(Te_a, 1);   // T_{l-1}
    if (l == 0) Tm1_a = 1.f;            // T_{-1} := T_0 = 1
    float T63 = __shfl(Te_a, 63);       // T_63
    float Tm1_b = __shfl_up(Te_b, 1);   // T_{63+l}
    if (l == 0) Tm1_b = T63;
    float v_a = 0.5f * (Tm1_a - Ti_a);
    float v_b = hb ? 0.5f * (Tm1_b - Ti_b) : 0.f;

    // weighted sums over samples
    float r_sum = v_a * c0_a + v_b * c0_b;
    float g_sum = v_a * c1_a + v_b * c1_b;
    float b_sum = v_a * c2_a + v_b * c2_b;
    float dep_sum = v_a * d_a + v_b * d_b;
#pragma unroll
    for (int off = 32; off >= 1; off >>= 1) {
        r_sum += __shfl_xor(r_sum, off);
        g_sum += __shfl_xor(g_sum, off);
        b_sum += __shfl_xor(b_sum, off);
        dep_sum += __shfl_xor(dep_sum, off);
    }

    // T_95 lives in lane 30's Ti_b (and lane 31's, since dd2_95 := 0).
    // Shuffle executed by all lanes (uniform), then used by lane 0.
    float T95 = __shfl(Ti_b, 31);

    // weights output
    float* wout = out_w + ray * SM;
    wout[l] = w_a;                    // midpoints 0..63
    if (l <= 30) wout[64 + l] = w_b;  // midpoints 64..94

    if (l == 0) {
        float rr = r_sum, gg = g_sum, bb = b_sum;
        if (*white_back) {
            float c = T95;  // 1 - wtot
            rr += c; gg += c; bb += c;
        }
        out_rgb[ray * 3 + 0] = rr;
        out_rgb[ray * 3 + 1] = gg;
        out_rgb[ray * 3 + 2] = bb;

        float gmin = __int_as_float((int)ws[0]);
        float gmax = __int_as_float((int)ws[1]);
        float cd = dep_sum;
        if (isnan(cd)) cd = INFINITY;          // nan_to_num(nan=inf)
        cd = fminf(fmaxf(cd, gmin), gmax);     // clip; inf -> gmax
        out_dep[ray] = cd;
    }
}

extern "C" void kernel_launch(void* const* d_in, const int* in_sizes, int n_in,
                              void* d_out, int out_size, void* d_ws, size_t ws_size,
                              hipStream_t stream) {
    const float* colors = (const float*)d_in[0];
    const float* dens = (const float*)d_in[1];
    const float* depths = (const float*)d_in[2];
    const int* white_back = (const int*)d_in[3];

    const int nrays = in_sizes[1] / S;  // densities: nrays * S
    unsigned int* ws = (unsigned int*)d_ws;

    float* out_rgb = (float*)d_out;                     // nrays*3
    float* out_dep = out_rgb + (size_t)nrays * 3;       // nrays
    float* out_w = out_dep + nrays;                     // nrays*95

    init_ws_kernel<<<1, 1, 0, stream>>>(ws);
    minmax_kernel<<<(nrays + 255) / 256, 256, 0, stream>>>(depths, ws, nrays);

    const int waves_per_block = 4;  // 256 threads
    const int blocks = (nrays + waves_per_block - 1) / waves_per_block;
    march_kernel<<<blocks, waves_per_block * 64, 0, stream>>>(
        colors, dens, depths, white_back, ws, out_rgb, out_dep, out_w, nrays);
}

// Round 4
// 62.650 us; speedup vs baseline: 1.2767x; 1.1553x over previous
//
#include <hip/hip_runtime.h>
#include <math.h>

#define S 96
#define SM 95   // S-1 midpoints
#define PT 8    // threads per ray
#define NS 12   // samples per thread (PT*NS == S)
#define L2E 1.4426950408889634f

__device__ __forceinline__ float fexp2(float x) {
#if __has_builtin(__builtin_amdgcn_exp2f)
    return __builtin_amdgcn_exp2f(x);   // v_exp_f32: 2^x
#else
    return exp2f(x);
#endif
}

__device__ __forceinline__ float flog2(float x) {
#if __has_builtin(__builtin_amdgcn_logf)
    return __builtin_amdgcn_logf(x);    // v_log_f32: log2(x)
#else
    return log2f(x);
#endif
}

// ---------------------------------------------------------------------------
// ws[0] = global min depth bits, ws[1] = global max depth bits (positive
// floats -> int bit-pattern ordering matches float ordering).
// ---------------------------------------------------------------------------
__global__ void init_ws_kernel(unsigned int* ws) {
    ws[0] = 0x7F800000u;  // +inf
    ws[1] = 0xFF800000u;  // -inf
}

// Depths sorted along sample axis: global min = min over rays of d[0],
// global max = max over rays of d[S-1].
__global__ void minmax_kernel(const float* __restrict__ depths,
                              unsigned int* __restrict__ ws, int nrays) {
    int r = blockIdx.x * blockDim.x + threadIdx.x;
    float dmin = INFINITY, dmax = -INFINITY;
    if (r < nrays) {
        dmin = depths[(size_t)r * S];
        dmax = depths[(size_t)r * S + (S - 1)];
    }
#pragma unroll
    for (int off = 32; off >= 1; off >>= 1) {
        dmin = fminf(dmin, __shfl_xor(dmin, off));
        dmax = fmaxf(dmax, __shfl_xor(dmax, off));
    }
    if ((threadIdx.x & 63) == 0) {
        atomicMin((int*)&ws[0], __float_as_int(dmin));
        atomicMax((int*)&ws[1], __float_as_int(dmax));
    }
}

// ---------------------------------------------------------------------------
// 8 threads per ray, 12 contiguous samples each (thread p owns samples
// 12p..12p+11 and midpoints 12p..12p+11; p=7 owns 11 midpoints).
//
// Log-space: dd2_i = (d_{i+1}-d_i) * log2(1+exp(x_i)), x_i = (s_i+s_{i+1})/2.
// Pass 1: per-thread serial cumsum of dd2 (kept in registers).
// Group scan (3 shfl_up over the 8-lane group) gives the exclusive base.
// Pass 2: T = exp2(-(base+cum)), w_i = T_prev - T_i; accumulate rgb/depth,
// then 3-step shfl_xor group reduction. wtot telescopes: 1-wtot = T_95.
// ---------------------------------------------------------------------------
__global__ __launch_bounds__(256) void march_kernel(
    const float* __restrict__ colors,
    const float* __restrict__ dens,
    const float* __restrict__ depths,
    const int* __restrict__ white_back,
    const unsigned int* __restrict__ ws,
    float* __restrict__ out_rgb,   // [nrays,3]
    float* __restrict__ out_dep,   // [nrays]
    float* __restrict__ out_w,     // [nrays,95]
    int nrays) {
    const int tid = blockIdx.x * blockDim.x + threadIdx.x;
    const int ray = tid >> 3;
    const int p = tid & 7;
    if (ray >= nrays) return;

    const float* db = depths + (size_t)ray * S + p * NS;
    const float* sb = dens + (size_t)ray * S + p * NS;
    const float* cb = colors + (size_t)ray * (S * 3) + p * (NS * 3);

    // vectorized per-thread loads (all 16B-aligned: 48B / 144B per-thread
    // segments; each 8-lane group covers its ray's rows contiguously)
    float d[NS], s[NS], c[NS * 3];
    {
        float4 t;
#pragma unroll
        for (int k = 0; k < 3; k++) {
            t = ((const float4*)db)[k];
            d[4 * k + 0] = t.x; d[4 * k + 1] = t.y;
            d[4 * k + 2] = t.z; d[4 * k + 3] = t.w;
            t = ((const float4*)sb)[k];
            s[4 * k + 0] = t.x; s[4 * k + 1] = t.y;
            s[4 * k + 2] = t.z; s[4 * k + 3] = t.w;
        }
#pragma unroll
        for (int k = 0; k < 9; k++) {
            t = ((const float4*)cb)[k];
            c[4 * k + 0] = t.x; c[4 * k + 1] = t.y;
            c[4 * k + 2] = t.z; c[4 * k + 3] = t.w;
        }
    }

    // neighbor (sample 12p+12) from lane+1; garbage at p==7 but masked there
    float dN = __shfl_down(d[0], 1);
    float sN = __shfl_down(s[0], 1);
    float cN0 = __shfl_down(c[0], 1);
    float cN1 = __shfl_down(c[1], 1);
    float cN2 = __shfl_down(c[2], 1);

    // ---- pass 1: dd2 + local cumsum
    const float C1 = 0.5f * L2E;
    float cum[NS];
    float run = 0.f;
#pragma unroll
    for (int i = 0; i < NS; i++) {
        float sn = (i < NS - 1) ? s[i + 1] : sN;
        float dn = (i < NS - 1) ? d[i + 1] : dN;
        float x2 = (s[i] + sn) * C1;                       // softplus arg * L2E
        float sp = fmaxf(x2, 0.f) + flog2(1.f + fexp2(-fabsf(x2)));
        float dd = (dn - d[i]) * sp;
        if (p == PT - 1 && i == NS - 1) dd = 0.f;          // midpoint 95 doesn't exist
        run += dd;
        cum[i] = run;
    }

    // ---- exclusive prefix over the 8-lane group
    float tot = run;
#pragma unroll
    for (int off = 1; off < PT; off <<= 1) {
        float q = __shfl_up(tot, off);
        if (p >= off) tot += q;
    }
    float base = tot - run;

    // group total -> T_95 (uniform shuffle, all lanes execute)
    const int lane = threadIdx.x & 63;
    float totAll = __shfl(tot, lane | 7);
    float T95 = fexp2(-totAll);

    // ---- pass 2: weights + accumulations
    float Tprev = fexp2(-base);   // T at sample 12p
    float racc = 0.f, gacc = 0.f, bacc = 0.f, dacc = 0.f;
    float* wout = out_w + (size_t)ray * SM + p * NS;
#pragma unroll
    for (int i = 0; i < NS; i++) {
        float T = fexp2(-(base + cum[i]));
        float wi = Tprev - T;
        Tprev = T;
        const bool valid = (p < PT - 1) || (i < NS - 1);
        if (!valid) wi = 0.f;
        float dn = (i < NS - 1) ? d[i + 1] : dN;
        float cn0 = (i < NS - 1) ? c[3 * i + 3] : cN0;
        float cn1 = (i < NS - 1) ? c[3 * i + 4] : cN1;
        float cn2 = (i < NS - 1) ? c[3 * i + 5] : cN2;
        racc += wi * (c[3 * i + 0] + cn0);
        gacc += wi * (c[3 * i + 1] + cn1);
        bacc += wi * (c[3 * i + 2] + cn2);
        dacc += wi * (d[i] + dn);
        if (valid) wout[i] = wi;
    }

    // ---- reduce rgb/depth across the 8-lane group
#pragma unroll
    for (int off = 1; off < PT; off <<= 1) {
        racc += __shfl_xor(racc, off);
        gacc += __shfl_xor(gacc, off);
        bacc += __shfl_xor(bacc, off);
        dacc += __shfl_xor(dacc, off);
    }

    if (p == 0) {
        float rr = 0.5f * racc, gg = 0.5f * gacc, bb = 0.5f * bacc;
        if (*white_back) {
            rr += T95; gg += T95; bb += T95;   // 1 - wtot = T_95
        }
        out_rgb[(size_t)ray * 3 + 0] = rr;
        out_rgb[(size_t)ray * 3 + 1] = gg;
        out_rgb[(size_t)ray * 3 + 2] = bb;

        float gmin = __int_as_float((int)ws[0]);
        float gmax = __int_as_float((int)ws[1]);
        float cd = 0.5f * dacc;
        if (isnan(cd)) cd = INFINITY;          // nan_to_num(nan=inf)
        cd = fminf(fmaxf(cd, gmin), gmax);     // clip; inf -> gmax
        out_dep[ray] = cd;
    }
}

extern "C" void kernel_launch(void* const* d_in, const int* in_sizes, int n_in,
                              void* d_out, int out_size, void* d_ws, size_t ws_size,
                              hipStream_t stream) {
    const float* colors = (const float*)d_in[0];
    const float* dens = (const float*)d_in[1];
    const float* depths = (const float*)d_in[2];
    const int* white_back = (const int*)d_in[3];

    const int nrays = in_sizes[1] / S;  // densities: nrays * S
    unsigned int* ws = (unsigned int*)d_ws;

    float* out_rgb = (float*)d_out;                     // nrays*3
    float* out_dep = out_rgb + (size_t)nrays * 3;       // nrays
    float* out_w = out_dep + nrays;                     // nrays*95

    init_ws_kernel<<<1, 1, 0, stream>>>(ws);
    minmax_kernel<<<(nrays + 255) / 256, 256, 0, stream>>>(depths, ws, nrays);

    const int nthreads = nrays * PT;
    const int blocks = (nthreads + 255) / 256;
    march_kernel<<<blocks, 256, 0, stream>>>(
        colors, dens, depths, white_back, ws, out_rgb, out_dep, out_w, nrays);
}